// Round 11
// baseline (616.492 us; speedup 1.0000x reference)
//
#include <hip/hip_runtime.h>
#include <hip/hip_bf16.h>
#include <cstdint>
#include <cstddef>
#include <cmath>

#define NEG_SLOPE 0.2f

// two-level multisplit CSR build params
#define PB  1024                 // pass-1 blocks (4 blocks/CU resident -> barriers overlap)
#define CSH 10                   // 1024 dsts per coarse bucket
#define CBS 1024
#define NBCMAX 160
#define PBN 2048                 // BN partial blocks (8/CU -> occupancy hides latency)

using frag = __attribute__((ext_vector_type(8))) short;   // 8 bf16 = 4 VGPRs
using facc = __attribute__((ext_vector_type(4))) float;   // 4 fp32 accum

__device__ __forceinline__ float bf_hi(unsigned u) {
    union { unsigned i; float f; } t; t.i = u & 0xffff0000u; return t.f;
}
__device__ __forceinline__ float bf_lo(unsigned u) {
    union { unsigned i; float f; } t; t.i = u << 16; return t.f;
}
__device__ __forceinline__ void unpack8(uint4 u, float* v) {
    v[0] = bf_lo(u.x); v[1] = bf_hi(u.x);
    v[2] = bf_lo(u.y); v[3] = bf_hi(u.y);
    v[4] = bf_lo(u.z); v[5] = bf_hi(u.z);
    v[6] = bf_lo(u.w); v[7] = bf_hi(u.w);
}

// async global->LDS, 16B per lane (wave-uniform LDS base + lane*16)
typedef const __attribute__((address_space(1))) void* gas_cptr;
typedef __attribute__((address_space(3))) void* las_ptr;
__device__ __forceinline__ void gload_lds16(const __hip_bfloat16* g, __hip_bfloat16* l) {
    __builtin_amdgcn_global_load_lds((gas_cptr)(const void*)g, (las_ptr)(void*)l, 16, 0, 0);
}

// ---------------------------------------------------------------- multisplit CSR build
__global__ __launch_bounds__(256)
void msplitA(const int* __restrict__ s0, const int* __restrict__ d0, int E0,
             const int* __restrict__ s1, const int* __restrict__ d1, int E1,
             const int* __restrict__ s2, const int* __restrict__ d2, int E2,
             int nc0, int nc1, int nc2, int cap0, int cap1, int cap2,
             int* __restrict__ stage, int* __restrict__ cnt2) {
    __shared__ int hist[NBCMAX];
    __shared__ int rbase[NBCMAX];
    __shared__ int curs[NBCMAX];
    __shared__ int ord[1024];
    __shared__ int obkt[1024];
    const int NBC = nc0 + nc1 + nc2;
    const long Etot = (long)E0 + E1 + E2;
    int tid = threadIdx.x;
    int lane = tid & 63;
    long chunk = (Etot + PB - 1) / PB;
    long c0 = (long)blockIdx.x * chunk;
    long c1 = c0 + chunk; if (c1 > Etot) c1 = Etot;
    const long sec1 = (long)PB * nc0 * cap0;
    const long sec2 = sec1 + (long)PB * nc1 * cap1;
    for (int t = tid; t < NBC; t += 256) curs[t] = 0;
    __syncthreads();
    for (long r0 = c0; r0 < c1; r0 += 1024) {
        int n = (int)((c1 - r0 < 1024) ? (c1 - r0) : 1024);
        for (int t = tid; t < NBC; t += 256) hist[t] = 0;
        __syncthreads();
        int mye[4], myb[4], myr[4];
#pragma unroll
        for (int k = 0; k < 4; ++k) {
            int li = k * 256 + tid;
            myb[k] = -1;
            if (li < n) {
                long i = r0 + li;
                int src, dst, gb;
                if (i < E0) { src = s0[i]; dst = d0[i]; gb = dst >> CSH; }
                else if (i < (long)E0 + E1) { long j = i - E0; src = s1[j]; dst = d1[j]; gb = nc0 + (dst >> CSH); }
                else { long j = i - E0 - E1; src = s2[j]; dst = d2[j]; gb = nc0 + nc1 + (dst >> CSH); }
                mye[k] = (src << CSH) | (dst & (CBS - 1));
                myb[k] = gb;
                myr[k] = atomicAdd(&hist[gb], 1);
            }
        }
        __syncthreads();
        if (tid < 64) {
            int carry = 0;
            for (int base = 0; base < NBC; base += 64) {
                int g = base + lane;
                int v = (g < NBC) ? hist[g] : 0;
                int sum = v;
#pragma unroll
                for (int o = 1; o < 64; o <<= 1) {
                    int t = __shfl_up(sum, o, 64);
                    if (lane >= o) sum += t;
                }
                if (g < NBC) rbase[g] = carry + sum - v;
                carry += __shfl(sum, 63, 64);
            }
        }
        __syncthreads();
#pragma unroll
        for (int k = 0; k < 4; ++k)
            if (myb[k] >= 0) {
                int pos = rbase[myb[k]] + myr[k];
                ord[pos] = mye[k];
                obkt[pos] = myb[k];
            }
        __syncthreads();
        for (int pos = tid; pos < n; pos += 256) {
            int b = obkt[pos];
            int rank = pos - rbase[b] + curs[b];
            long addr; int cap;
            if (b < nc0)            { cap = cap0; addr = (long)(blockIdx.x * nc0 + b) * cap0; }
            else if (b < nc0 + nc1) { cap = cap1; addr = sec1 + (long)(blockIdx.x * nc1 + (b - nc0)) * cap1; }
            else                    { cap = cap2; addr = sec2 + (long)(blockIdx.x * nc2 + (b - nc0 - nc1)) * cap2; }
            if (rank < cap) stage[addr + rank] = ord[pos];
        }
        __syncthreads();
        for (int t = tid; t < NBC; t += 256) curs[t] += hist[t];
        __syncthreads();
    }
    for (int t = tid; t < NBC; t += 256) {
        int cap = (t < nc0) ? cap0 : (t < nc0 + nc1) ? cap1 : cap2;
        int c = curs[t]; if (c > cap) c = cap;
        cnt2[(long)blockIdx.x * NBC + t] = c;
    }
}

__global__ void scanC1(const int* __restrict__ cnt2, int* __restrict__ tot, int NBC) {
    __shared__ int red[256];
    int gb = blockIdx.x;
    int tid = threadIdx.x;
    int s = 0;
    for (int p = tid; p < PB; p += 256) s += cnt2[(long)p * NBC + gb];
    red[tid] = s;
    __syncthreads();
    for (int o = 128; o; o >>= 1) {
        if (tid < o) red[tid] += red[tid + o];
        __syncthreads();
    }
    if (tid == 0) tot[gb] = red[0];
}

__global__ void scanC2(const int* __restrict__ tot, int* __restrict__ cstart,
                       int NBC, int nc0, int nc1) {
    if (threadIdx.x == 0) {
        int c = 0;
        for (int gb = 0; gb < NBC; ++gb) {
            if (gb == nc0 || gb == nc0 + nc1) c = 0;
            cstart[gb] = c;
            c += tot[gb];
        }
    }
}

__global__ __launch_bounds__(1024)
void fineB(const int* __restrict__ cnt2, const int* __restrict__ cstart,
           const int* __restrict__ stage,
           int nc0, int nc1, int nc2, int cap0, int cap1, int cap2,
           int* __restrict__ off0, int* __restrict__ col0, int n0,
           int* __restrict__ off1, int* __restrict__ col1, int n1,
           int* __restrict__ off2, int* __restrict__ col2, int n2) {
    __shared__ int fragb[PB + 1];
    __shared__ int cnt[1024];
    __shared__ int wsum[17];
    const int NBC = nc0 + nc1 + nc2;
    int gb = blockIdx.x;
    int tid = threadIdx.x;
    int lane = tid & 63;
    int wv = tid >> 6;
    int cb, ncg, n; long base2, stride; int* off; int* col;
    const long sec1 = (long)PB * nc0 * cap0;
    const long sec2 = sec1 + (long)PB * nc1 * cap1;
    if (gb < nc0) {
        cb = gb; ncg = nc0; n = n0; off = off0; col = col0;
        base2 = (long)cb * cap0; stride = (long)nc0 * cap0;
    } else if (gb < nc0 + nc1) {
        cb = gb - nc0; ncg = nc1; n = n1; off = off1; col = col1;
        base2 = sec1 + (long)cb * cap1; stride = (long)nc1 * cap1;
    } else {
        cb = gb - nc0 - nc1; ncg = nc2; n = n2; off = off2; col = col2;
        base2 = sec2 + (long)cb * cap2; stride = (long)nc2 * cap2;
    }
    int dlo = cb << CSH;
    int colbase = cstart[gb];
    int v = cnt2[(long)tid * NBC + gb];
    int sum = v;
#pragma unroll
    for (int o = 1; o < 64; o <<= 1) {
        int t = __shfl_up(sum, o, 64);
        if (lane >= o) sum += t;
    }
    if (lane == 63) wsum[wv] = sum;
    __syncthreads();
    if (tid == 0) {
        int c = 0;
        for (int w = 0; w < 16; ++w) { int t = wsum[w]; wsum[w] = c; c += t; }
        wsum[16] = c;
    }
    __syncthreads();
    fragb[tid] = wsum[wv] + sum - v;
    if (tid == 0) fragb[PB] = wsum[16];
    __syncthreads();
    int sz = fragb[PB];
    cnt[tid] = 0;
    __syncthreads();
    for (int p = tid; p < sz; p += 1024) {
        int lo = 0, hi = PB;
        while (hi - lo > 1) { int mid = (lo + hi) >> 1; if (fragb[mid] <= p) lo = mid; else hi = mid; }
        int e = stage[base2 + (long)lo * stride + (p - fragb[lo])];
        atomicAdd(&cnt[e & (CBS - 1)], 1);
    }
    __syncthreads();
    int cv = cnt[tid];
    int csum = cv;
#pragma unroll
    for (int o = 1; o < 64; o <<= 1) {
        int t = __shfl_up(csum, o, 64);
        if (lane >= o) csum += t;
    }
    if (lane == 63) wsum[wv] = csum;
    __syncthreads();
    if (tid == 0) {
        int c = 0;
        for (int w = 0; w < 16; ++w) { int t = wsum[w]; wsum[w] = c; c += t; }
    }
    __syncthreads();
    int excl = wsum[wv] + csum - cv;
    int d = dlo + tid;
    if (d < n) off[d] = colbase + excl;
    if (cb == ncg - 1 && tid == 0) off[n] = colbase + sz;
    __syncthreads();
    cnt[tid] = colbase + excl;      // cursors
    __syncthreads();
    for (int p = tid; p < sz; p += 1024) {
        int lo = 0, hi = PB;
        while (hi - lo > 1) { int mid = (lo + hi) >> 1; if (fragb[mid] <= p) lo = mid; else hi = mid; }
        int e = stage[base2 + (long)lo * stride + (p - fragb[lo])];
        int pos = atomicAdd(&cnt[e & (CBS - 1)], 1);
        col[pos] = e >> CSH;
    }
}

// ---------------------------------------------------------------- bf16 MFMA GEMM (templated)
// Full-K panel staging (one barrier for KP<=160) + operand-swapped MFMA so each
// lane holds 4 consecutive columns -> 8B vector stores. (R10: gemms left top-5.)
template<int KP, int KSTEP>
__global__ __launch_bounds__(256)
void gemm_t(const __hip_bfloat16* __restrict__ A,
            const __hip_bfloat16* __restrict__ Bt,
            __hip_bfloat16* __restrict__ C,
            const float* __restrict__ bias, int M, int N) {
    constexpr int CPR = KSTEP / 8;          // 16B chunks per row
    constexpr int ITER = CPR / 2;           // staging iters per tile per thread
    __shared__ __hip_bfloat16 As[128 * KSTEP];
    __shared__ __hip_bfloat16 Bs[128 * KSTEP];
    int tid = threadIdx.x;
    int lane = tid & 63;
    int wave = tid >> 6;
    int wm = wave >> 1, wn = wave & 1;
    int quad = lane >> 4, l16 = lane & 15;
    int m0 = blockIdx.y * 128;
    int n0 = blockIdx.x * 128;

    facc acc[4][4] = {};

    for (int k0 = 0; k0 < KP; k0 += KSTEP) {
        if (k0) __syncthreads();            // protect LDS reuse (KP>KSTEP only)
#pragma unroll
        for (int p = 0; p < ITER; ++p) {
            int idx = p * 256 + tid;        // chunk id, linear == LDS position
            int row = idx / CPR;            // compile-time-constant division
            int c = idx - row * CPR;
            int gr = m0 + row; if (gr >= M) gr = M - 1;
            int lbase = (p * 256 + wave * 64) * 8;   // wave-uniform LDS base
            gload_lds16(A + (size_t)gr * KP + k0 + c * 8, As + lbase);
            gload_lds16(Bt + (size_t)(n0 + row) * KP + k0 + c * 8, Bs + lbase);
        }
        __syncthreads();   // single vmcnt drain per panel
#pragma unroll
        for (int kk = 0; kk < KSTEP / 32; ++kk) {
            frag a[4], b[4];
#pragma unroll
            for (int i = 0; i < 4; ++i) {
                a[i] = *(const frag*)(As + (wm * 64 + i * 16 + l16) * KSTEP + kk * 32 + quad * 8);
                b[i] = *(const frag*)(Bs + (wn * 64 + i * 16 + l16) * KSTEP + kk * 32 + quad * 8);
            }
#pragma unroll
            for (int i = 0; i < 4; ++i)
#pragma unroll
                for (int j = 0; j < 4; ++j)
                    acc[i][j] = __builtin_amdgcn_mfma_f32_16x16x32_bf16(b[j], a[i], acc[i][j], 0, 0, 0);
        }
    }

    // swapped C/D: m = m0+wm*64+i*16+l16, n = n0+wn*64+j*16+quad*4 (+reg)
    float4 bv[4];
#pragma unroll
    for (int j = 0; j < 4; ++j) {
        int n = n0 + wn * 64 + j * 16 + quad * 4;
        if (bias != nullptr) bv[j] = *(const float4*)(bias + n);
        else { bv[j].x = 0.f; bv[j].y = 0.f; bv[j].z = 0.f; bv[j].w = 0.f; }
    }
#pragma unroll
    for (int i = 0; i < 4; ++i) {
        int m = m0 + wm * 64 + i * 16 + l16;
        if (m >= M) continue;
#pragma unroll
        for (int j = 0; j < 4; ++j) {
            int n = n0 + wn * 64 + j * 16 + quad * 4;
            union { uint2 u; __hip_bfloat16 hh[4]; } pk;
            pk.hh[0] = __float2bfloat16(acc[i][j][0] + bv[j].x);
            pk.hh[1] = __float2bfloat16(acc[i][j][1] + bv[j].y);
            pk.hh[2] = __float2bfloat16(acc[i][j][2] + bv[j].z);
            pk.hh[3] = __float2bfloat16(acc[i][j][3] + bv[j].w);
            *(uint2*)(C + (size_t)m * N + n) = pk.u;   // 8B vector store
        }
    }
}

// YL/YR[M,2] fp32 = (A*s+t)[M,K](bf16,BN-folded inline) @ {Wl,Wr}[K,2](fp32)
__global__ void gemm_n22_bn(const __hip_bfloat16* __restrict__ A,
                            const float* __restrict__ Wl, const float* __restrict__ Wr,
                            const float* __restrict__ s, const float* __restrict__ t,
                            float* __restrict__ YL, float* __restrict__ YR, int M, int K) {
    int i = blockIdx.x * blockDim.x + threadIdx.x;
    if (i >= M) return;
    float l0 = 0.f, l1 = 0.f, r0 = 0.f, r1 = 0.f;
    const unsigned* a = (const unsigned*)(A + (size_t)i * K);
    for (int k2 = 0; k2 < K / 2; ++k2) {
        unsigned u = a[k2];
        int k = k2 * 2;
        float v0 = fmaf(bf_lo(u), s[k], t[k]);          // BN applied in f32
        float v1 = fmaf(bf_hi(u), s[k + 1], t[k + 1]);
        l0 = fmaf(v0, Wl[k * 2 + 0], l0);
        l1 = fmaf(v0, Wl[k * 2 + 1], l1);
        l0 = fmaf(v1, Wl[k * 2 + 2], l0);
        l1 = fmaf(v1, Wl[k * 2 + 3], l1);
        r0 = fmaf(v0, Wr[k * 2 + 0], r0);
        r1 = fmaf(v0, Wr[k * 2 + 1], r1);
        r0 = fmaf(v1, Wr[k * 2 + 2], r0);
        r1 = fmaf(v1, Wr[k * 2 + 3], r1);
    }
    YL[(size_t)i * 2 + 0] = l0;
    YL[(size_t)i * 2 + 1] = l1;
    YR[(size_t)i * 2 + 0] = r0;
    YR[(size_t)i * 2 + 1] = r1;
}

// ---------------------------------------------------------------- batched prep
__global__ void prep_all(const float* __restrict__ l1Wl, const float* __restrict__ l1Wr,
                         const float* __restrict__ lhWl,
                         const float* __restrict__ h1Wl, const float* __restrict__ h1Wr,
                         const float* __restrict__ x_low, const float* __restrict__ x_high,
                         const float* __restrict__ lhWr, const float* __restrict__ z_std,
                         __hip_bfloat16* __restrict__ w_l1, __hip_bfloat16* __restrict__ w_lh,
                         __hip_bfloat16* __restrict__ w_h1,
                         __hip_bfloat16* __restrict__ XLOWB, __hip_bfloat16* __restrict__ XRo,
                         __hip_bfloat16* __restrict__ EHB,
                         int o1, int o2, int o3, int o4, int o5, int o6, int o7, int o8) {
    int i = blockIdx.x * blockDim.x + threadIdx.x;
    if (i < o1) {                              // xconv: N_low x 128 (pad 125->128)
        int r = i >> 7, c = i & 127;
        XLOWB[i] = __float2bfloat16((c < 125) ? x_low[(size_t)r * 125 + c] : 0.f);
    } else if (i < o2) {                       // outer_xr: N_high x 128
        int j = i - o1; int r = j >> 7, c = j & 127;
        XRo[j] = __float2bfloat16(x_high[r] * lhWr[c]);
    } else if (i < o3) {                       // EHB cols 128..159: z + zero pad
        int j = i - o2; int r = j >> 5, c = (j & 31) + 128;
        EHB[(size_t)r * 160 + c] = __float2bfloat16((c == 128) ? z_std[r] : 0.f);
    } else if (i < o4) {                       // w_l1 Wl [256][128], K=125
        int j = i - o3; int n = j >> 7, k = j & 127;
        w_l1[j] = __float2bfloat16((k < 125) ? l1Wl[(size_t)k * 256 + n] : 0.f);
    } else if (i < o5) {                       // w_l1 Wr
        int j = i - o4; int n = j >> 7, k = j & 127;
        w_l1[256 * 128 + j] = __float2bfloat16((k < 125) ? l1Wr[(size_t)k * 256 + n] : 0.f);
    } else if (i < o6) {                       // w_lh [128][128], K=128
        int j = i - o5; int n = j >> 7, k = j & 127;
        w_lh[j] = __float2bfloat16(lhWl[(size_t)k * 128 + n]);
    } else if (i < o7) {                       // w_h1 Wl perm [256][160]
        int j = i - o6; int n = j / 160, k = j - n * 160;
        float v = 0.f;
        if (k < 128) v = h1Wl[(size_t)(k + 1) * 256 + n];
        else if (k == 128) v = h1Wl[n];
        w_h1[j] = __float2bfloat16(v);
    } else if (i < o8) {                       // w_h1 Wr perm
        int j = i - o7; int n = j / 160, k = j - n * 160;
        float v = 0.f;
        if (k < 128) v = h1Wr[(size_t)(k + 1) * 256 + n];
        else if (k == 128) v = h1Wr[n];
        w_h1[256 * 160 + j] = __float2bfloat16(v);
    }
}

// BN-folded weight transpose, both Wl and Wr via blockIdx.y (reads bnsc):
__global__ void wconv_bnfold2(const float* __restrict__ Wl, const float* __restrict__ Wr,
                              const float* __restrict__ scale, const float* __restrict__ shift,
                              __hip_bfloat16* __restrict__ Wt, float* __restrict__ bout,
                              int K, int N, int Kp) {
    __shared__ float red[256];
    const float* W = blockIdx.y ? Wr : Wl;
    __hip_bfloat16* wt = Wt + (size_t)blockIdx.y * N * Kp;
    float* bo = bout + blockIdx.y * N;
    int n = blockIdx.x;
    int tid = threadIdx.x;
    float acc = 0.f;
    for (int k = tid; k < Kp; k += 256) {
        float v = 0.f;
        if (k < K) {
            float w = W[(size_t)k * N + n];
            v = w * scale[k];
            acc = fmaf(w, shift[k], acc);
        }
        wt[(size_t)n * Kp + k] = __float2bfloat16(v);
    }
    red[tid] = acc;
    __syncthreads();
    for (int o = 128; o; o >>= 1) {
        if (tid < o) red[tid] += red[tid + o];
        __syncthreads();
    }
    if (tid == 0) bo[n] = red[0];
}

// ---------------------------------------------------------------- fused GATv2, H=1, PAIR-DST
// One wave = 2 dsts. Per dst: 2 edge slots x 16 lanes (8 channels each).
// Halves wave count + fixed per-wave cost (prologue/merge/store); merge tree
// is 1 xor level (16) instead of v4's 2. Loop runs to max(deg1,deg2) with
// per-lane validity (w=0 for finished/empty dsts).
__global__ void gat_c128_p2(const __hip_bfloat16* __restrict__ xl, int xls,
                            const __hip_bfloat16* __restrict__ xr, int xrs,
                            const int* __restrict__ row_off, const int* __restrict__ col,
                            const float* __restrict__ att, const float* __restrict__ bias,
                            __hip_bfloat16* __restrict__ outb, int obstride,
                            int n_dst) {
    int pair = (blockIdx.x * blockDim.x + threadIdx.x) >> 6;
    int lane = threadIdx.x & 63;
    int d = pair * 2 + (lane >> 5);      // this half-wave's dst
    int g = (lane >> 4) & 1;             // edge slot 0..1
    int q = lane & 15;                   // channels 8q..8q+7
    int cb = q * 8;
    bool dvalid = d < n_dst;
    int dd = dvalid ? d : (n_dst - 1);
    int beg = row_off[dd], end = row_off[dd + 1];
    int deg = dvalid ? (end - beg) : 0;
    int md = deg;
    md = max(md, __shfl_xor(md, 32, 64));    // wave max degree

    float xrv[8], av[8];
    unpack8(*(const uint4*)(xr + (size_t)dd * xrs + cb), xrv);
    {
        float4 a0 = *(const float4*)(att + cb);
        float4 a1 = *(const float4*)(att + cb + 4);
        av[0] = a0.x; av[1] = a0.y; av[2] = a0.z; av[3] = a0.w;
        av[4] = a1.x; av[5] = a1.y; av[6] = a1.z; av[7] = a1.w;
    }

    float s = 0.f;
    float acc[8] = {0.f, 0.f, 0.f, 0.f, 0.f, 0.f, 0.f, 0.f};

    if (md > 0) {
        // depth-2 pipeline over chunks of 2 edges per dst
        bool pv = (g) < deg;
        int i0 = pv ? col[beg + g] : 0;
        uint4 u = *(const uint4*)(xl + (size_t)i0 * xls + cb);
        int i1 = 0;
        if (2 < md) { bool p1 = (2 + g) < deg; i1 = p1 ? col[beg + 2 + g] : 0; }

        for (int e = 0; e < md; e += 2) {
            bool have_next = (e + 2) < md;
            uint4 un;
            if (have_next)
                un = *(const uint4*)(xl + (size_t)i1 * xls + cb);   // issue early
            int i2 = 0;
            if (e + 4 < md) { bool p2 = (e + 4 + g) < deg; i2 = p2 ? col[beg + e + 4 + g] : 0; }
            bool nv = (e + 2 + g) < deg;

            float v[8];
            unpack8(u, v);
            float p = 0.f;
#pragma unroll
            for (int c = 0; c < 8; ++c) {
                float z = v[c] + xrv[c];
                z = fmaxf(z, NEG_SLOPE * z);    // leaky-relu, slope<1
                p = fmaf(z, av[c], p);
            }
            p += __shfl_xor(p, 8, 64);          // reduce within 16-lane group
            p += __shfl_xor(p, 4, 64);
            p += __shfl_xor(p, 2, 64);
            p += __shfl_xor(p, 1, 64);
            if (!pv) p = -INFINITY;
            float w = __expf(fminf(p, 85.f));   // 0 for invalid slots
            s += w;
#pragma unroll
            for (int c = 0; c < 8; ++c) acc[c] = fmaf(w, v[c], acc[c]);

            if (have_next) { u = un; pv = nv; }
            i1 = i2;
        }
    }

    // merge the 2 slots of this dst (lane^16 stays within the 32-lane half)
    s += __shfl_xor(s, 16, 64);
#pragma unroll
    for (int c = 0; c < 8; ++c) acc[c] += __shfl_xor(acc[c], 16, 64);

    float inv = (deg > 0) ? 1.f / (s * (float)deg) : 0.f;
    float o8[8];
#pragma unroll
    for (int c = 0; c < 8; ++c) o8[c] = acc[c] * inv;
    if (bias != nullptr) {
#pragma unroll
        for (int c = 0; c < 8; ++c) o8[c] += bias[cb + c];
    }
    if (g == 0 && dvalid) {
        union { uint4 u; __hip_bfloat16 hh[8]; } pk;
#pragma unroll
        for (int c = 0; c < 8; ++c) pk.hh[c] = __float2bfloat16(o8[c]);
        *(uint4*)(outb + (size_t)d * obstride + cb) = pk.u;
    }
}

// ---------------------------------------------------------------- fused GATv2, H=2 head-paired
// One wave per dst, BOTH heads; v11: DEPTH-3 pipeline (2 bursts buffered + 3rd
// index prefetched) — only 2 edges in flight was the residual latency exposure.
__global__ void gat_c256h2(const __hip_bfloat16* __restrict__ xl, int xls,
                           const __hip_bfloat16* __restrict__ xr, int xrs,
                           const int* __restrict__ row_off, const int* __restrict__ col,
                           const float* __restrict__ att, const float* __restrict__ bias,
                           __hip_bfloat16* __restrict__ outb, int obstride,
                           int n_dst) {
    int dst = (blockIdx.x * blockDim.x + threadIdx.x) >> 6;
    int lane = threadIdx.x & 63;
    if (dst >= n_dst) return;
    int g = lane >> 5;        // edge slot 0..1
    int q = lane & 31;        // channel block: channels 8q..8q+7 (head = q>>4)
    int cb = q * 8;
    int beg = row_off[dst], end = row_off[dst + 1];
    int deg = end - beg;

    float xrv[8], av[8];
    unpack8(*(const uint4*)(xr + (size_t)dst * xrs + cb), xrv);
    {
        float4 a0 = *(const float4*)(att + cb);
        float4 a1 = *(const float4*)(att + cb + 4);
        av[0] = a0.x; av[1] = a0.y; av[2] = a0.z; av[3] = a0.w;
        av[4] = a1.x; av[5] = a1.y; av[6] = a1.z; av[7] = a1.w;
    }

    float s = 0.f;
    float acc[8] = {0.f, 0.f, 0.f, 0.f, 0.f, 0.f, 0.f, 0.f};

    if (deg > 0) {
        bool pv0 = g < deg;
        int i0 = col[pv0 ? beg + g : beg];
        uint4 u0 = *(const uint4*)(xl + (size_t)i0 * xls + cb);
        bool pv1 = (2 + g) < deg;
        uint4 u1;
        if (2 < deg) {
            int i1 = col[pv1 ? beg + 2 + g : beg];
            u1 = *(const uint4*)(xl + (size_t)i1 * xls + cb);
        }
        int i2 = (4 < deg) ? col[((4 + g) < deg) ? beg + 4 + g : beg] : 0;

        for (int e = 0; e < deg; e += 2) {
            bool has2 = (e + 4) < deg;
            uint4 u2;
            if (has2)
                u2 = *(const uint4*)(xl + (size_t)i2 * xls + cb);   // issue early
            int i3 = ((e + 6) < deg) ? col[((e + 6 + g) < deg) ? beg + e + 6 + g : beg] : 0;
            bool pv2 = (e + 4 + g) < deg;

            float v[8];
            unpack8(u0, v);
            float p = 0.f;
#pragma unroll
            for (int c = 0; c < 8; ++c) {
                float z = v[c] + xrv[c];
                z = fmaxf(z, NEG_SLOPE * z);    // leaky-relu, slope<1
                p = fmaf(z, av[c], p);
            }
            // reduce within the 16-lane head group
            p += __shfl_xor(p, 8, 64);
            p += __shfl_xor(p, 4, 64);
            p += __shfl_xor(p, 2, 64);
            p += __shfl_xor(p, 1, 64);
            if (!pv0) p = -INFINITY;
            float w = __expf(fminf(p, 85.f));   // per-(edge,head) weight
            s += w;
#pragma unroll
            for (int c = 0; c < 8; ++c) acc[c] = fmaf(w, v[c], acc[c]);

            u0 = u1; pv0 = pv1;
            u1 = u2; pv1 = pv2;
            i2 = i3;
        }
    }

    // merge the 2 edge slots (lane^32 holds matching (head,channel))
    s += __shfl_xor(s, 32, 64);
#pragma unroll
    for (int c = 0; c < 8; ++c) acc[c] += __shfl_xor(acc[c], 32, 64);

    float inv = (deg > 0) ? 1.f / (s * (float)deg) : 0.f;
    float o8[8];
#pragma unroll
    for (int c = 0; c < 8; ++c) o8[c] = acc[c] * inv;
    if (bias != nullptr) {
#pragma unroll
        for (int c = 0; c < 8; ++c) o8[c] += bias[cb + c];
    }
    if (g == 0) {
        union { uint4 u; __hip_bfloat16 hh[8]; } pk;
#pragma unroll
        for (int c = 0; c < 8; ++c) pk.hh[c] = __float2bfloat16(o8[c]);
        *(uint4*)(outb + (size_t)dst * obstride + cb) = pk.u;   // 512B contiguous
    }
}

// C=2, H=1 final layer: one thread per dst (fp32 xl/xr).
__global__ void gat_c2(const float* __restrict__ xl, const float* __restrict__ xr,
                       const int* __restrict__ row_off, const int* __restrict__ col,
                       const float* __restrict__ att, const float* __restrict__ bias,
                       float* __restrict__ out, int n_dst) {
    int dst = blockIdx.x * blockDim.x + threadIdx.x;
    if (dst >= n_dst) return;
    float x0 = xr[(size_t)dst * 2], x1 = xr[(size_t)dst * 2 + 1];
    float a0 = att[0], a1 = att[1];
    int beg = row_off[dst], end = row_off[dst + 1];
    float s = 0.f, acc0 = 0.f, acc1 = 0.f;
    for (int e = beg; e < end; ++e) {
        int src = col[e];
        float v0 = xl[(size_t)src * 2], v1 = xl[(size_t)src * 2 + 1];
        float z0 = v0 + x0; z0 = fmaxf(z0, NEG_SLOPE * z0);
        float z1 = v1 + x1; z1 = fmaxf(z1, NEG_SLOPE * z1);
        float p = fmaf(z0, a0, z1 * a1);
        float w = __expf(fminf(p, 85.f));
        s += w;
        acc0 = fmaf(w, v0, acc0);
        acc1 = fmaf(w, v1, acc1);
    }
    int deg = end - beg;
    float o0 = 0.f, o1 = 0.f;
    if (deg > 0) {
        float inv = 1.f / (s * (float)deg);
        o0 = acc0 * inv;
        o1 = acc1 * inv;
    }
    out[(size_t)dst * 2 + 0] = o0 + bias[0];
    out[(size_t)dst * 2 + 1] = o1 + bias[1];
}

// ---------------------------------------------------------------- BatchNorm stats (deterministic)
// PBN=2048 partial blocks (8/CU; 256 blocks was 9.7% occ, latency-bound).
__global__ void bn_partial_d(const __hip_bfloat16* __restrict__ x, float* __restrict__ part,
                             int Nr, int rpb) {
    int C = blockDim.x;
    int c = threadIdx.x;
    int b = blockIdx.x;
    int r0 = b * rpb;
    int r1 = r0 + rpb; if (r1 > Nr) r1 = Nr;
    float s = 0.f, q = 0.f;
    for (int r = r0; r < r1; ++r) {
        float v = __bfloat162float(x[(size_t)r * C + c]);
        s += v;
        q = fmaf(v, v, q);
    }
    part[(size_t)b * C + c] = s;
    part[(size_t)PBN * 256 + (size_t)b * C + c] = q;
}

// one wave per channel; lanes sum PBN/64=32 partials each, fixed-order tree.
__global__ void bn_finalize_w(const float* __restrict__ part,
                              const float* __restrict__ g, const float* __restrict__ b,
                              float* __restrict__ scale, float* __restrict__ shift,
                              int Nr, int C) {
    int c = (blockIdx.x * blockDim.x + threadIdx.x) >> 6;
    int lane = threadIdx.x & 63;
    if (c >= C) return;
    float s = 0.f, q = 0.f;
    for (int blk = lane; blk < PBN; blk += 64) {
        s += part[(size_t)blk * C + c];
        q += part[(size_t)PBN * 256 + (size_t)blk * C + c];
    }
#pragma unroll
    for (int o = 32; o; o >>= 1) {
        s += __shfl_xor(s, o, 64);
        q += __shfl_xor(q, o, 64);
    }
    if (lane == 0) {
        float mu = s / (float)Nr;
        float var = q / (float)Nr - mu * mu;
        float inv = rsqrtf(var + 1e-5f);
        float a = g[c] * inv;
        scale[c] = a;
        shift[c] = b[c] - mu * a;
    }
}

// ---------------------------------------------------------------- driver
extern "C" void kernel_launch(void* const* d_in, const int* in_sizes, int n_in,
                              void* d_out, int out_size, void* d_ws, size_t ws_size,
                              hipStream_t stream) {
    const float* x_low  = (const float*)d_in[0];
    const float* x_high = (const float*)d_in[1];
    const float* z_std  = (const float*)d_in[2];
    const int* e_low  = (const int*)d_in[3];
    const int* e_l2h  = (const int*)d_in[4];
    const int* e_high = (const int*)d_in[5];
    const float* l1_Wl = (const float*)d_in[6];
    const float* l1_Wr = (const float*)d_in[7];
    const float* l1_att = (const float*)d_in[8];
    const float* l1_b  = (const float*)d_in[9];
    const float* bn1_g = (const float*)d_in[10];
    const float* bn1_b = (const float*)d_in[11];
    const float* l2_Wl = (const float*)d_in[12];
    const float* l2_Wr = (const float*)d_in[13];
    const float* l2_att = (const float*)d_in[14];
    const float* l2_b  = (const float*)d_in[15];
    const float* bn2_g = (const float*)d_in[16];
    const float* bn2_b = (const float*)d_in[17];
    const float* l3_Wl = (const float*)d_in[18];
    const float* l3_Wr = (const float*)d_in[19];
    const float* l3_att = (const float*)d_in[20];
    const float* l3_b  = (const float*)d_in[21];
    const float* lh_Wl = (const float*)d_in[22];
    const float* lh_Wr = (const float*)d_in[23];
    const float* lh_att = (const float*)d_in[24];
    const float* h1_Wl = (const float*)d_in[25];
    const float* h1_Wr = (const float*)d_in[26];
    const float* h1_att = (const float*)d_in[27];
    const float* h1_b  = (const float*)d_in[28];
    const float* bn3_g = (const float*)d_in[29];
    const float* bn3_b = (const float*)d_in[30];
    const float* h2_Wl = (const float*)d_in[31];
    const float* h2_Wr = (const float*)d_in[32];
    const float* h2_att = (const float*)d_in[33];
    const float* h2_b  = (const float*)d_in[34];
    const float* bn4_g = (const float*)d_in[35];
    const float* bn4_b = (const float*)d_in[36];
    const float* h3_Wl = (const float*)d_in[37];
    const float* h3_Wr = (const float*)d_in[38];
    const float* h3_att = (const float*)d_in[39];
    const float* h3_b  = (const float*)d_in[40];

    const int N_low = in_sizes[0] / 125;
    const int N_high = in_sizes[1];
    const int E_low = in_sizes[3] / 2;
    const int E_l2h = in_sizes[4] / 2;
    const int E_high = in_sizes[5] / 2;

    char* ws = (char*)d_ws;
    size_t woff = 0;
    auto walloc = [&](size_t bytes) -> void* {
        void* p = (void*)(ws + woff);
        woff += (bytes + 255) & ~(size_t)255;
        return p;
    };
    __hip_bfloat16* XLR = (__hip_bfloat16*)walloc((size_t)N_high * 512 * 2);
    __hip_bfloat16* A1  = (__hip_bfloat16*)walloc((size_t)N_high * 256 * 2);
    __hip_bfloat16* A2  = (__hip_bfloat16*)walloc((size_t)N_high * 128 * 2);
    __hip_bfloat16* XRo = (__hip_bfloat16*)walloc((size_t)N_high * 128 * 2); // lh outer xr
    __hip_bfloat16* XLOWB = (__hip_bfloat16*)walloc((size_t)N_low * 128 * 2);
    __hip_bfloat16* EHB = (__hip_bfloat16*)walloc((size_t)N_high * 160 * 2);
    float* YL = (float*)walloc((size_t)N_high * 2 * 4);
    float* YR = (float*)walloc((size_t)N_high * 2 * 4);
    int* off_low  = (int*)walloc((size_t)(N_low + 1) * 4);
    int* col_low  = (int*)walloc((size_t)E_low * 4);
    int* off_l2h  = (int*)walloc((size_t)(N_high + 1) * 4);
    int* col_l2h  = (int*)walloc((size_t)E_l2h * 4);
    int* off_high = (int*)walloc((size_t)(N_high + 1) * 4);
    int* col_high = (int*)walloc((size_t)E_high * 4);
    // multisplit CSR state
    const int nc0 = (N_low + CBS - 1) >> CSH;
    const int nc1 = (N_high + CBS - 1) >> CSH;
    const int nc2 = (N_high + CBS - 1) >> CSH;
    const int NBC = nc0 + nc1 + nc2;
    const long Etot = (long)E_low + E_l2h + E_high;
    const long chunk = (Etot + PB - 1) / PB;
    auto capf = [&](int ng) {
        double m = (double)chunk * CBS / ng;
        int c = (int)(m + 8.0 * sqrt(m) + 16.0);
        return (c + 15) & ~15;
    };
    const int cap0 = capf(N_low);
    const int cap1 = capf(N_high);
    const int cap2 = capf(N_high);
    int* cnt2   = (int*)walloc((size_t)PB * NBC * 4);
    int* cstart = (int*)walloc((size_t)(NBC + 1) * 4);
    int* ctot   = (int*)walloc((size_t)(NBC + 1) * 4);
    float* bnpart = (float*)walloc((size_t)2 * PBN * 256 * 4);   // deterministic BN partials
    float* bnsc   = (float*)walloc(512 * 4);             // scale | shift
    float* bb     = (float*)walloc(512 * 4);             // folded gemm bias
    __hip_bfloat16* w_l1 = (__hip_bfloat16*)walloc(512 * 128 * 2);
    __hip_bfloat16* w_l2 = (__hip_bfloat16*)walloc(256 * 256 * 2);
    __hip_bfloat16* w_l3 = (__hip_bfloat16*)walloc(256 * 128 * 2);
    __hip_bfloat16* w_lh = (__hip_bfloat16*)walloc(128 * 128 * 2);
    __hip_bfloat16* w_h1 = (__hip_bfloat16*)walloc(512 * 160 * 2);
    __hip_bfloat16* w_h2 = (__hip_bfloat16*)walloc(256 * 256 * 2);

    int* stage = (int*)XLR;   // PB=1024: ~52 MB needed, 61 MB available; dead until first gemm

    // ---- batched prep
    {
        int o1 = N_low * 128;              // xconv
        int o2 = o1 + N_high * 128;        // outer_xr
        int o3 = o2 + N_high * 32;         // EHB cols 128..159
        int o4 = o3 + 256 * 128;           // w_l1 Wl
        int o5 = o4 + 256 * 128;           // w_l1 Wr
        int o6 = o5 + 128 * 128;           // w_lh
        int o7 = o6 + 256 * 160;           // w_h1 Wl
        int o8 = o7 + 256 * 160;           // w_h1 Wr
        prep_all<<<(o8 + 255) / 256, 256, 0, stream>>>(
            l1_Wl, l1_Wr, lh_Wl, h1_Wl, h1_Wr, x_low, x_high, lh_Wr, z_std,
            w_l1, w_lh, w_h1, XLOWB, XRo, EHB,
            o1, o2, o3, o4, o5, o6, o7, o8);
    }

    // ---- multisplit CSR build for all 3 graphs (4 launches, no global atomics)
    msplitA<<<PB, 256, 0, stream>>>(
        e_low, e_low + E_low, E_low,
        e_l2h, e_l2h + E_l2h, E_l2h,
        e_high, e_high + E_high, E_high,
        nc0, nc1, nc2, cap0, cap1, cap2, stage, cnt2);
    scanC1<<<NBC, 256, 0, stream>>>(cnt2, ctot, NBC);
    scanC2<<<1, 64, 0, stream>>>(ctot, cstart, NBC, nc0, nc1);
    fineB<<<NBC, 1024, 0, stream>>>(cnt2, cstart, stage,
                                    nc0, nc1, nc2, cap0, cap1, cap2,
                                    off_low, col_low, N_low,
                                    off_l2h, col_l2h, N_high,
                                    off_high, col_high, N_high);

    auto gemm = [&](const __hip_bfloat16* A, const __hip_bfloat16* Bt, __hip_bfloat16* C,
                    int M, int N, int Kp, const float* bias) {
        dim3 g(N / 128, (M + 127) / 128);
        if (Kp == 128)      gemm_t<128, 128><<<g, 256, 0, stream>>>(A, Bt, C, bias, M, N);
        else if (Kp == 160) gemm_t<160, 160><<<g, 256, 0, stream>>>(A, Bt, C, bias, M, N);
        else                gemm_t<256, 128><<<g, 256, 0, stream>>>(A, Bt, C, bias, M, N);
    };
    auto gat1 = [&](const __hip_bfloat16* xl, int xls, const __hip_bfloat16* xr, int xrs,
                    const int* roff, const int* colv,
                    const float* att, const float* bias,
                    __hip_bfloat16* outb, int obs, int n_dst) {
        long waves = (n_dst + 1) / 2;
        long thr = waves * 64;
        gat_c128_p2<<<(unsigned)((thr + 255) / 256), 256, 0, stream>>>(
            xl, xls, xr, xrs, roff, colv, att, bias, outb, obs, n_dst);
    };
    auto gat2 = [&](const __hip_bfloat16* xl, int xls, const __hip_bfloat16* xr, int xrs,
                    const int* roff, const int* colv,
                    const float* att, const float* bias,
                    __hip_bfloat16* outb, int obs, int n_dst) {
        long thr = (long)n_dst * 64;
        gat_c256h2<<<(unsigned)((thr + 255) / 256), 256, 0, stream>>>(
            xl, xls, xr, xrs, roff, colv, att, bias, outb, obs, n_dst);
    };
    // deterministic BN stats (PBN-parallel partials + wave-per-channel finalize)
    auto bn_stats = [&](__hip_bfloat16* x, const float* g, const float* b, int Nr, int C) {
        int rpb = (Nr + PBN - 1) / PBN;
        bn_partial_d<<<PBN, C, 0, stream>>>(x, bnpart, Nr, rpb);
        bn_finalize_w<<<(C * 64 + 255) / 256, 256, 0, stream>>>(bnpart, g, b, bnsc, bnsc + 256, Nr, C);
    };
    // fold bn (bnsc) into a merged [Wl|Wr] weight + bias pair (one launch)
    auto fold2 = [&](const float* Wl, const float* Wr, __hip_bfloat16* Wt,
                     int K, int Nn, int Kp) {
        dim3 g(Nn, 2);
        wconv_bnfold2<<<g, 256, 0, stream>>>(Wl, Wr, bnsc, bnsc + 256, Wt, bb, K, Nn, Kp);
    };

    // ---- low_net layer 1: 125 -> (H=2) 256   (merged [XL|XR], stride 512)
    gemm(XLOWB, w_l1, XLR, N_low, 512, 128, nullptr);
    gat2(XLR, 512, XLR + 256, 512, off_low, col_low, l1_att, l1_b, A1, 256, N_low);
    bn_stats(A1, bn1_g, bn1_b, N_low, 256);

    // ---- low_net layer 2: 256 -> 128 (BN1 folded into w_l2 + bias)
    fold2(l2_Wl, l2_Wr, w_l2, 256, 128, 256);
    gemm(A1, w_l2, XLR, N_low, 256, 256, bb);
    gat1(XLR, 256, XLR + 128, 256, off_low, col_low, l2_att, l2_b, A2, 128, N_low);
    bn_stats(A2, bn2_g, bn2_b, N_low, 128);

    // ---- low_net layer 3: 128 -> 128 (BN2 folded into w_l3 + bias)
    fold2(l3_Wl, l3_Wr, w_l3, 128, 128, 128);
    gemm(A2, w_l3, XLR, N_low, 256, 128, bb);
    gat1(XLR, 256, XLR + 128, 256, off_low, col_low, l3_att, l3_b, A1, 128, N_low);

    // ---- bipartite low2high -> EHB[N_high][160] = [gat 0..127 | z | pad] (pad/z pre-inited)
    gemm(A1, w_lh, XLR, N_low, 128, 128, nullptr);   // xl only, stride 128
    gat1(XLR, 128, XRo, 128, off_l2h, col_l2h, lh_att, nullptr, EHB, 160, N_high);

    // ---- high_net layer 1: 129(perm,pad160) -> (H=2) 256   (merged, stride 512)
    gemm(EHB, w_h1, XLR, N_high, 512, 160, nullptr);
    gat2(XLR, 512, XLR + 256, 512, off_high, col_high, h1_att, h1_b, A1, 256, N_high);
    bn_stats(A1, bn3_g, bn3_b, N_high, 256);

    // ---- high_net layer 2: 256 -> 128 (BN3 folded into w_h2 + bias)
    fold2(h2_Wl, h2_Wr, w_h2, 256, 128, 256);
    gemm(A1, w_h2, XLR, N_high, 256, 256, bb);
    gat1(XLR, 256, XLR + 128, 256, off_high, col_high, h2_att, h2_b, A2, 128, N_high);
    bn_stats(A2, bn4_g, bn4_b, N_high, 128);

    // ---- high_net layer 3: 128 -> 2 (BN4 applied inline in f32; one pass over A2)
    gemm_n22_bn<<<(N_high + 255) / 256, 256, 0, stream>>>(A2, h3_Wl, h3_Wr,
                                                          bnsc, bnsc + 256, YL, YR, N_high, 128);
    gat_c2<<<(N_high + 255) / 256, 256, 0, stream>>>(YL, YR, off_high, col_high,
                                                     h3_att, h3_b, (float*)d_out, N_high);
}

// Round 12
// 602.582 us; speedup vs baseline: 1.0231x; 1.0231x over previous
//
#include <hip/hip_runtime.h>
#include <hip/hip_bf16.h>
#include <cstdint>
#include <cstddef>
#include <cmath>

#define NEG_SLOPE 0.2f

// two-level multisplit CSR build params
#define PB  1024                 // pass-1 blocks (4 blocks/CU resident -> barriers overlap)
#define CSH 10                   // 1024 dsts per coarse bucket
#define CBS 1024
#define NBCMAX 160
#define PBN 2048                 // BN partial blocks (8/CU -> occupancy hides latency)

using frag = __attribute__((ext_vector_type(8))) short;   // 8 bf16 = 4 VGPRs
using facc = __attribute__((ext_vector_type(4))) float;   // 4 fp32 accum

__device__ __forceinline__ float bf_hi(unsigned u) {
    union { unsigned i; float f; } t; t.i = u & 0xffff0000u; return t.f;
}
__device__ __forceinline__ float bf_lo(unsigned u) {
    union { unsigned i; float f; } t; t.i = u << 16; return t.f;
}
__device__ __forceinline__ void unpack8(uint4 u, float* v) {
    v[0] = bf_lo(u.x); v[1] = bf_hi(u.x);
    v[2] = bf_lo(u.y); v[3] = bf_hi(u.y);
    v[4] = bf_lo(u.z); v[5] = bf_hi(u.z);
    v[6] = bf_lo(u.w); v[7] = bf_hi(u.w);
}

// async global->LDS, 16B per lane (wave-uniform LDS base + lane*16)
typedef const __attribute__((address_space(1))) void* gas_cptr;
typedef __attribute__((address_space(3))) void* las_ptr;
__device__ __forceinline__ void gload_lds16(const __hip_bfloat16* g, __hip_bfloat16* l) {
    __builtin_amdgcn_global_load_lds((gas_cptr)(const void*)g, (las_ptr)(void*)l, 16, 0, 0);
}

// ---------------------------------------------------------------- multisplit CSR build
__global__ __launch_bounds__(256)
void msplitA(const int* __restrict__ s0, const int* __restrict__ d0, int E0,
             const int* __restrict__ s1, const int* __restrict__ d1, int E1,
             const int* __restrict__ s2, const int* __restrict__ d2, int E2,
             int nc0, int nc1, int nc2, int cap0, int cap1, int cap2,
             int* __restrict__ stage, int* __restrict__ cnt2) {
    __shared__ int hist[NBCMAX];
    __shared__ int rbase[NBCMAX];
    __shared__ int curs[NBCMAX];
    __shared__ int ord[1024];
    __shared__ int obkt[1024];
    const int NBC = nc0 + nc1 + nc2;
    const long Etot = (long)E0 + E1 + E2;
    int tid = threadIdx.x;
    int lane = tid & 63;
    long chunk = (Etot + PB - 1) / PB;
    long c0 = (long)blockIdx.x * chunk;
    long c1 = c0 + chunk; if (c1 > Etot) c1 = Etot;
    const long sec1 = (long)PB * nc0 * cap0;
    const long sec2 = sec1 + (long)PB * nc1 * cap1;
    for (int t = tid; t < NBC; t += 256) curs[t] = 0;
    __syncthreads();
    for (long r0 = c0; r0 < c1; r0 += 1024) {
        int n = (int)((c1 - r0 < 1024) ? (c1 - r0) : 1024);
        for (int t = tid; t < NBC; t += 256) hist[t] = 0;
        __syncthreads();
        int mye[4], myb[4], myr[4];
#pragma unroll
        for (int k = 0; k < 4; ++k) {
            int li = k * 256 + tid;
            myb[k] = -1;
            if (li < n) {
                long i = r0 + li;
                int src, dst, gb;
                if (i < E0) { src = s0[i]; dst = d0[i]; gb = dst >> CSH; }
                else if (i < (long)E0 + E1) { long j = i - E0; src = s1[j]; dst = d1[j]; gb = nc0 + (dst >> CSH); }
                else { long j = i - E0 - E1; src = s2[j]; dst = d2[j]; gb = nc0 + nc1 + (dst >> CSH); }
                mye[k] = (src << CSH) | (dst & (CBS - 1));
                myb[k] = gb;
                myr[k] = atomicAdd(&hist[gb], 1);
            }
        }
        __syncthreads();
        if (tid < 64) {
            int carry = 0;
            for (int base = 0; base < NBC; base += 64) {
                int g = base + lane;
                int v = (g < NBC) ? hist[g] : 0;
                int sum = v;
#pragma unroll
                for (int o = 1; o < 64; o <<= 1) {
                    int t = __shfl_up(sum, o, 64);
                    if (lane >= o) sum += t;
                }
                if (g < NBC) rbase[g] = carry + sum - v;
                carry += __shfl(sum, 63, 64);
            }
        }
        __syncthreads();
#pragma unroll
        for (int k = 0; k < 4; ++k)
            if (myb[k] >= 0) {
                int pos = rbase[myb[k]] + myr[k];
                ord[pos] = mye[k];
                obkt[pos] = myb[k];
            }
        __syncthreads();
        for (int pos = tid; pos < n; pos += 256) {
            int b = obkt[pos];
            int rank = pos - rbase[b] + curs[b];
            long addr; int cap;
            if (b < nc0)            { cap = cap0; addr = (long)(blockIdx.x * nc0 + b) * cap0; }
            else if (b < nc0 + nc1) { cap = cap1; addr = sec1 + (long)(blockIdx.x * nc1 + (b - nc0)) * cap1; }
            else                    { cap = cap2; addr = sec2 + (long)(blockIdx.x * nc2 + (b - nc0 - nc1)) * cap2; }
            if (rank < cap) stage[addr + rank] = ord[pos];
        }
        __syncthreads();
        for (int t = tid; t < NBC; t += 256) curs[t] += hist[t];
        __syncthreads();
    }
    for (int t = tid; t < NBC; t += 256) {
        int cap = (t < nc0) ? cap0 : (t < nc0 + nc1) ? cap1 : cap2;
        int c = curs[t]; if (c > cap) c = cap;
        cnt2[(long)blockIdx.x * NBC + t] = c;
    }
}

__global__ void scanC1(const int* __restrict__ cnt2, int* __restrict__ tot, int NBC) {
    __shared__ int red[256];
    int gb = blockIdx.x;
    int tid = threadIdx.x;
    int s = 0;
    for (int p = tid; p < PB; p += 256) s += cnt2[(long)p * NBC + gb];
    red[tid] = s;
    __syncthreads();
    for (int o = 128; o; o >>= 1) {
        if (tid < o) red[tid] += red[tid + o];
        __syncthreads();
    }
    if (tid == 0) tot[gb] = red[0];
}

__global__ void scanC2(const int* __restrict__ tot, int* __restrict__ cstart,
                       int NBC, int nc0, int nc1) {
    if (threadIdx.x == 0) {
        int c = 0;
        for (int gb = 0; gb < NBC; ++gb) {
            if (gb == nc0 || gb == nc0 + nc1) c = 0;
            cstart[gb] = c;
            c += tot[gb];
        }
    }
}

__global__ __launch_bounds__(1024)
void fineB(const int* __restrict__ cnt2, const int* __restrict__ cstart,
           const int* __restrict__ stage,
           int nc0, int nc1, int nc2, int cap0, int cap1, int cap2,
           int* __restrict__ off0, int* __restrict__ col0, int n0,
           int* __restrict__ off1, int* __restrict__ col1, int n1,
           int* __restrict__ off2, int* __restrict__ col2, int n2) {
    __shared__ int fragb[PB + 1];
    __shared__ int cnt[1024];
    __shared__ int wsum[17];
    const int NBC = nc0 + nc1 + nc2;
    int gb = blockIdx.x;
    int tid = threadIdx.x;
    int lane = tid & 63;
    int wv = tid >> 6;
    int cb, ncg, n; long base2, stride; int* off; int* col;
    const long sec1 = (long)PB * nc0 * cap0;
    const long sec2 = sec1 + (long)PB * nc1 * cap1;
    if (gb < nc0) {
        cb = gb; ncg = nc0; n = n0; off = off0; col = col0;
        base2 = (long)cb * cap0; stride = (long)nc0 * cap0;
    } else if (gb < nc0 + nc1) {
        cb = gb - nc0; ncg = nc1; n = n1; off = off1; col = col1;
        base2 = sec1 + (long)cb * cap1; stride = (long)nc1 * cap1;
    } else {
        cb = gb - nc0 - nc1; ncg = nc2; n = n2; off = off2; col = col2;
        base2 = sec2 + (long)cb * cap2; stride = (long)nc2 * cap2;
    }
    int dlo = cb << CSH;
    int colbase = cstart[gb];
    int v = cnt2[(long)tid * NBC + gb];
    int sum = v;
#pragma unroll
    for (int o = 1; o < 64; o <<= 1) {
        int t = __shfl_up(sum, o, 64);
        if (lane >= o) sum += t;
    }
    if (lane == 63) wsum[wv] = sum;
    __syncthreads();
    if (tid == 0) {
        int c = 0;
        for (int w = 0; w < 16; ++w) { int t = wsum[w]; wsum[w] = c; c += t; }
        wsum[16] = c;
    }
    __syncthreads();
    fragb[tid] = wsum[wv] + sum - v;
    if (tid == 0) fragb[PB] = wsum[16];
    __syncthreads();
    int sz = fragb[PB];
    cnt[tid] = 0;
    __syncthreads();
    for (int p = tid; p < sz; p += 1024) {
        int lo = 0, hi = PB;
        while (hi - lo > 1) { int mid = (lo + hi) >> 1; if (fragb[mid] <= p) lo = mid; else hi = mid; }
        int e = stage[base2 + (long)lo * stride + (p - fragb[lo])];
        atomicAdd(&cnt[e & (CBS - 1)], 1);
    }
    __syncthreads();
    int cv = cnt[tid];
    int csum = cv;
#pragma unroll
    for (int o = 1; o < 64; o <<= 1) {
        int t = __shfl_up(csum, o, 64);
        if (lane >= o) csum += t;
    }
    if (lane == 63) wsum[wv] = csum;
    __syncthreads();
    if (tid == 0) {
        int c = 0;
        for (int w = 0; w < 16; ++w) { int t = wsum[w]; wsum[w] = c; c += t; }
    }
    __syncthreads();
    int excl = wsum[wv] + csum - cv;
    int d = dlo + tid;
    if (d < n) off[d] = colbase + excl;
    if (cb == ncg - 1 && tid == 0) off[n] = colbase + sz;
    __syncthreads();
    cnt[tid] = colbase + excl;      // cursors
    __syncthreads();
    for (int p = tid; p < sz; p += 1024) {
        int lo = 0, hi = PB;
        while (hi - lo > 1) { int mid = (lo + hi) >> 1; if (fragb[mid] <= p) lo = mid; else hi = mid; }
        int e = stage[base2 + (long)lo * stride + (p - fragb[lo])];
        int pos = atomicAdd(&cnt[e & (CBS - 1)], 1);
        col[pos] = e >> CSH;
    }
}

// ---------------------------------------------------------------- bf16 MFMA GEMM (templated)
// Full-K panel staging (one barrier for KP<=160) + operand-swapped MFMA so each
// lane holds 4 consecutive columns -> 8B vector stores.
template<int KP, int KSTEP>
__global__ __launch_bounds__(256)
void gemm_t(const __hip_bfloat16* __restrict__ A,
            const __hip_bfloat16* __restrict__ Bt,
            __hip_bfloat16* __restrict__ C,
            const float* __restrict__ bias, int M, int N) {
    constexpr int CPR = KSTEP / 8;          // 16B chunks per row
    constexpr int ITER = CPR / 2;           // staging iters per tile per thread
    __shared__ __hip_bfloat16 As[128 * KSTEP];
    __shared__ __hip_bfloat16 Bs[128 * KSTEP];
    int tid = threadIdx.x;
    int lane = tid & 63;
    int wave = tid >> 6;
    int wm = wave >> 1, wn = wave & 1;
    int quad = lane >> 4, l16 = lane & 15;
    int m0 = blockIdx.y * 128;
    int n0 = blockIdx.x * 128;

    facc acc[4][4] = {};

    for (int k0 = 0; k0 < KP; k0 += KSTEP) {
        if (k0) __syncthreads();            // protect LDS reuse (KP>KSTEP only)
#pragma unroll
        for (int p = 0; p < ITER; ++p) {
            int idx = p * 256 + tid;        // chunk id, linear == LDS position
            int row = idx / CPR;            // compile-time-constant division
            int c = idx - row * CPR;
            int gr = m0 + row; if (gr >= M) gr = M - 1;
            int lbase = (p * 256 + wave * 64) * 8;   // wave-uniform LDS base
            gload_lds16(A + (size_t)gr * KP + k0 + c * 8, As + lbase);
            gload_lds16(Bt + (size_t)(n0 + row) * KP + k0 + c * 8, Bs + lbase);
        }
        __syncthreads();   // single vmcnt drain per panel
#pragma unroll
        for (int kk = 0; kk < KSTEP / 32; ++kk) {
            frag a[4], b[4];
#pragma unroll
            for (int i = 0; i < 4; ++i) {
                a[i] = *(const frag*)(As + (wm * 64 + i * 16 + l16) * KSTEP + kk * 32 + quad * 8);
                b[i] = *(const frag*)(Bs + (wn * 64 + i * 16 + l16) * KSTEP + kk * 32 + quad * 8);
            }
#pragma unroll
            for (int i = 0; i < 4; ++i)
#pragma unroll
                for (int j = 0; j < 4; ++j)
                    acc[i][j] = __builtin_amdgcn_mfma_f32_16x16x32_bf16(b[j], a[i], acc[i][j], 0, 0, 0);
        }
    }

    // swapped C/D: m = m0+wm*64+i*16+l16, n = n0+wn*64+j*16+quad*4 (+reg)
    float4 bv[4];
#pragma unroll
    for (int j = 0; j < 4; ++j) {
        int n = n0 + wn * 64 + j * 16 + quad * 4;
        if (bias != nullptr) bv[j] = *(const float4*)(bias + n);
        else { bv[j].x = 0.f; bv[j].y = 0.f; bv[j].z = 0.f; bv[j].w = 0.f; }
    }
#pragma unroll
    for (int i = 0; i < 4; ++i) {
        int m = m0 + wm * 64 + i * 16 + l16;
        if (m >= M) continue;
#pragma unroll
        for (int j = 0; j < 4; ++j) {
            int n = n0 + wn * 64 + j * 16 + quad * 4;
            union { uint2 u; __hip_bfloat16 hh[4]; } pk;
            pk.hh[0] = __float2bfloat16(acc[i][j][0] + bv[j].x);
            pk.hh[1] = __float2bfloat16(acc[i][j][1] + bv[j].y);
            pk.hh[2] = __float2bfloat16(acc[i][j][2] + bv[j].z);
            pk.hh[3] = __float2bfloat16(acc[i][j][3] + bv[j].w);
            *(uint2*)(C + (size_t)m * N + n) = pk.u;   // 8B vector store
        }
    }
}

// YL/YR[M,2] fp32 = (A*s+t)[M,K](bf16,BN-folded inline) @ {Wl,Wr}[K,2](fp32)
__global__ void gemm_n22_bn(const __hip_bfloat16* __restrict__ A,
                            const float* __restrict__ Wl, const float* __restrict__ Wr,
                            const float* __restrict__ s, const float* __restrict__ t,
                            float* __restrict__ YL, float* __restrict__ YR, int M, int K) {
    int i = blockIdx.x * blockDim.x + threadIdx.x;
    if (i >= M) return;
    float l0 = 0.f, l1 = 0.f, r0 = 0.f, r1 = 0.f;
    const unsigned* a = (const unsigned*)(A + (size_t)i * K);
    for (int k2 = 0; k2 < K / 2; ++k2) {
        unsigned u = a[k2];
        int k = k2 * 2;
        float v0 = fmaf(bf_lo(u), s[k], t[k]);          // BN applied in f32
        float v1 = fmaf(bf_hi(u), s[k + 1], t[k + 1]);
        l0 = fmaf(v0, Wl[k * 2 + 0], l0);
        l1 = fmaf(v0, Wl[k * 2 + 1], l1);
        l0 = fmaf(v1, Wl[k * 2 + 2], l0);
        l1 = fmaf(v1, Wl[k * 2 + 3], l1);
        r0 = fmaf(v0, Wr[k * 2 + 0], r0);
        r1 = fmaf(v0, Wr[k * 2 + 1], r1);
        r0 = fmaf(v1, Wr[k * 2 + 2], r0);
        r1 = fmaf(v1, Wr[k * 2 + 3], r1);
    }
    YL[(size_t)i * 2 + 0] = l0;
    YL[(size_t)i * 2 + 1] = l1;
    YR[(size_t)i * 2 + 0] = r0;
    YR[(size_t)i * 2 + 1] = r1;
}

// ---------------------------------------------------------------- batched prep
__global__ void prep_all(const float* __restrict__ l1Wl, const float* __restrict__ l1Wr,
                         const float* __restrict__ lhWl,
                         const float* __restrict__ h1Wl, const float* __restrict__ h1Wr,
                         const float* __restrict__ x_low, const float* __restrict__ x_high,
                         const float* __restrict__ lhWr, const float* __restrict__ z_std,
                         __hip_bfloat16* __restrict__ w_l1, __hip_bfloat16* __restrict__ w_lh,
                         __hip_bfloat16* __restrict__ w_h1,
                         __hip_bfloat16* __restrict__ XLOWB, __hip_bfloat16* __restrict__ XRo,
                         __hip_bfloat16* __restrict__ EHB,
                         int o1, int o2, int o3, int o4, int o5, int o6, int o7, int o8) {
    int i = blockIdx.x * blockDim.x + threadIdx.x;
    if (i < o1) {                              // xconv: N_low x 128 (pad 125->128)
        int r = i >> 7, c = i & 127;
        XLOWB[i] = __float2bfloat16((c < 125) ? x_low[(size_t)r * 125 + c] : 0.f);
    } else if (i < o2) {                       // outer_xr: N_high x 128
        int j = i - o1; int r = j >> 7, c = j & 127;
        XRo[j] = __float2bfloat16(x_high[r] * lhWr[c]);
    } else if (i < o3) {                       // EHB cols 128..159: z + zero pad
        int j = i - o2; int r = j >> 5, c = (j & 31) + 128;
        EHB[(size_t)r * 160 + c] = __float2bfloat16((c == 128) ? z_std[r] : 0.f);
    } else if (i < o4) {                       // w_l1 Wl [256][128], K=125
        int j = i - o3; int n = j >> 7, k = j & 127;
        w_l1[j] = __float2bfloat16((k < 125) ? l1Wl[(size_t)k * 256 + n] : 0.f);
    } else if (i < o5) {                       // w_l1 Wr
        int j = i - o4; int n = j >> 7, k = j & 127;
        w_l1[256 * 128 + j] = __float2bfloat16((k < 125) ? l1Wr[(size_t)k * 256 + n] : 0.f);
    } else if (i < o6) {                       // w_lh [128][128], K=128
        int j = i - o5; int n = j >> 7, k = j & 127;
        w_lh[j] = __float2bfloat16(lhWl[(size_t)k * 128 + n]);
    } else if (i < o7) {                       // w_h1 Wl perm [256][160]
        int j = i - o6; int n = j / 160, k = j - n * 160;
        float v = 0.f;
        if (k < 128) v = h1Wl[(size_t)(k + 1) * 256 + n];
        else if (k == 128) v = h1Wl[n];
        w_h1[j] = __float2bfloat16(v);
    } else if (i < o8) {                       // w_h1 Wr perm
        int j = i - o7; int n = j / 160, k = j - n * 160;
        float v = 0.f;
        if (k < 128) v = h1Wr[(size_t)(k + 1) * 256 + n];
        else if (k == 128) v = h1Wr[n];
        w_h1[256 * 160 + j] = __float2bfloat16(v);
    }
}

// BN-folded weight transpose, both Wl and Wr via blockIdx.y (reads bnsc):
__global__ void wconv_bnfold2(const float* __restrict__ Wl, const float* __restrict__ Wr,
                              const float* __restrict__ scale, const float* __restrict__ shift,
                              __hip_bfloat16* __restrict__ Wt, float* __restrict__ bout,
                              int K, int N, int Kp) {
    __shared__ float red[256];
    const float* W = blockIdx.y ? Wr : Wl;
    __hip_bfloat16* wt = Wt + (size_t)blockIdx.y * N * Kp;
    float* bo = bout + blockIdx.y * N;
    int n = blockIdx.x;
    int tid = threadIdx.x;
    float acc = 0.f;
    for (int k = tid; k < Kp; k += 256) {
        float v = 0.f;
        if (k < K) {
            float w = W[(size_t)k * N + n];
            v = w * scale[k];
            acc = fmaf(w, shift[k], acc);
        }
        wt[(size_t)n * Kp + k] = __float2bfloat16(v);
    }
    red[tid] = acc;
    __syncthreads();
    for (int o = 128; o; o >>= 1) {
        if (tid < o) red[tid] += red[tid + o];
        __syncthreads();
    }
    if (tid == 0) bo[n] = red[0];
}

// ---------------------------------------------------------------- fused GATv2, H=1, PAIR-DST
// One wave = 2 dsts, 2 edge slots x 16 lanes each. (R11: inferred ~-5us net
// across the 4 H=1 layers.)
__global__ void gat_c128_p2(const __hip_bfloat16* __restrict__ xl, int xls,
                            const __hip_bfloat16* __restrict__ xr, int xrs,
                            const int* __restrict__ row_off, const int* __restrict__ col,
                            const float* __restrict__ att, const float* __restrict__ bias,
                            __hip_bfloat16* __restrict__ outb, int obstride,
                            int n_dst) {
    int pair = (blockIdx.x * blockDim.x + threadIdx.x) >> 6;
    int lane = threadIdx.x & 63;
    int d = pair * 2 + (lane >> 5);      // this half-wave's dst
    int g = (lane >> 4) & 1;             // edge slot 0..1
    int q = lane & 15;                   // channels 8q..8q+7
    int cb = q * 8;
    bool dvalid = d < n_dst;
    int dd = dvalid ? d : (n_dst - 1);
    int beg = row_off[dd], end = row_off[dd + 1];
    int deg = dvalid ? (end - beg) : 0;
    int md = deg;
    md = max(md, __shfl_xor(md, 32, 64));    // wave max degree

    float xrv[8], av[8];
    unpack8(*(const uint4*)(xr + (size_t)dd * xrs + cb), xrv);
    {
        float4 a0 = *(const float4*)(att + cb);
        float4 a1 = *(const float4*)(att + cb + 4);
        av[0] = a0.x; av[1] = a0.y; av[2] = a0.z; av[3] = a0.w;
        av[4] = a1.x; av[5] = a1.y; av[6] = a1.z; av[7] = a1.w;
    }

    float s = 0.f;
    float acc[8] = {0.f, 0.f, 0.f, 0.f, 0.f, 0.f, 0.f, 0.f};

    if (md > 0) {
        // depth-2 pipeline over chunks of 2 edges per dst
        bool pv = (g) < deg;
        int i0 = pv ? col[beg + g] : 0;
        uint4 u = *(const uint4*)(xl + (size_t)i0 * xls + cb);
        int i1 = 0;
        if (2 < md) { bool p1 = (2 + g) < deg; i1 = p1 ? col[beg + 2 + g] : 0; }

        for (int e = 0; e < md; e += 2) {
            bool have_next = (e + 2) < md;
            uint4 un;
            if (have_next)
                un = *(const uint4*)(xl + (size_t)i1 * xls + cb);   // issue early
            int i2 = 0;
            if (e + 4 < md) { bool p2 = (e + 4 + g) < deg; i2 = p2 ? col[beg + e + 4 + g] : 0; }
            bool nv = (e + 2 + g) < deg;

            float v[8];
            unpack8(u, v);
            float p = 0.f;
#pragma unroll
            for (int c = 0; c < 8; ++c) {
                float z = v[c] + xrv[c];
                z = fmaxf(z, NEG_SLOPE * z);    // leaky-relu, slope<1
                p = fmaf(z, av[c], p);
            }
            p += __shfl_xor(p, 8, 64);          // reduce within 16-lane group
            p += __shfl_xor(p, 4, 64);
            p += __shfl_xor(p, 2, 64);
            p += __shfl_xor(p, 1, 64);
            if (!pv) p = -INFINITY;
            float w = __expf(fminf(p, 85.f));   // 0 for invalid slots
            s += w;
#pragma unroll
            for (int c = 0; c < 8; ++c) acc[c] = fmaf(w, v[c], acc[c]);

            if (have_next) { u = un; pv = nv; }
            i1 = i2;
        }
    }

    // merge the 2 slots of this dst (lane^16 stays within the 32-lane half)
    s += __shfl_xor(s, 16, 64);
#pragma unroll
    for (int c = 0; c < 8; ++c) acc[c] += __shfl_xor(acc[c], 16, 64);

    float inv = (deg > 0) ? 1.f / (s * (float)deg) : 0.f;
    float o8[8];
#pragma unroll
    for (int c = 0; c < 8; ++c) o8[c] = acc[c] * inv;
    if (bias != nullptr) {
#pragma unroll
        for (int c = 0; c < 8; ++c) o8[c] += bias[cb + c];
    }
    if (g == 0 && dvalid) {
        union { uint4 u; __hip_bfloat16 hh[8]; } pk;
#pragma unroll
        for (int c = 0; c < 8; ++c) pk.hh[c] = __float2bfloat16(o8[c]);
        *(uint4*)(outb + (size_t)d * obstride + cb) = pk.u;
    }
}

// ---------------------------------------------------------------- fused GATv2, H=2 head-paired
// One wave per dst, BOTH heads. DEPTH-2 pipeline — R10's exact form (46.8us);
// depth-3 measured a regression twice (R11: 52.7us, VALUBusy 85->73%).
__global__ void gat_c256h2(const __hip_bfloat16* __restrict__ xl, int xls,
                           const __hip_bfloat16* __restrict__ xr, int xrs,
                           const int* __restrict__ row_off, const int* __restrict__ col,
                           const float* __restrict__ att, const float* __restrict__ bias,
                           __hip_bfloat16* __restrict__ outb, int obstride,
                           int n_dst) {
    int dst = (blockIdx.x * blockDim.x + threadIdx.x) >> 6;
    int lane = threadIdx.x & 63;
    if (dst >= n_dst) return;
    int g = lane >> 5;        // edge slot 0..1
    int q = lane & 31;        // channel block: channels 8q..8q+7 (head = q>>4)
    int cb = q * 8;
    int beg = row_off[dst], end = row_off[dst + 1];

    float xrv[8], av[8];
    unpack8(*(const uint4*)(xr + (size_t)dst * xrs + cb), xrv);
    {
        float4 a0 = *(const float4*)(att + cb);
        float4 a1 = *(const float4*)(att + cb + 4);
        av[0] = a0.x; av[1] = a0.y; av[2] = a0.z; av[3] = a0.w;
        av[4] = a1.x; av[5] = a1.y; av[6] = a1.z; av[7] = a1.w;
    }

    float s = 0.f;
    float acc[8] = {0.f, 0.f, 0.f, 0.f, 0.f, 0.f, 0.f, 0.f};

    if (beg < end) {
        int e0g = beg + g;
        bool pv = e0g < end;
        int i0 = col[pv ? e0g : beg];
        uint4 u = *(const uint4*)(xl + (size_t)i0 * xls + cb);
        int e1g = beg + 2 + g;
        int i1 = (beg + 2 < end) ? col[(e1g < end) ? e1g : beg] : 0;

        for (int e0 = beg; e0 < end; e0 += 2) {
            bool have_next = (e0 + 2) < end;
            uint4 un;
            if (have_next)
                un = *(const uint4*)(xl + (size_t)i1 * xls + cb);   // issue early
            int e2g = e0 + 4 + g;
            int i2 = (e0 + 4 < end) ? col[(e2g < end) ? e2g : beg] : 0;
            bool nv = (e0 + 2 + g) < end;

            float v[8];
            unpack8(u, v);
            float p = 0.f;
#pragma unroll
            for (int c = 0; c < 8; ++c) {
                float z = v[c] + xrv[c];
                z = fmaxf(z, NEG_SLOPE * z);    // leaky-relu, slope<1
                p = fmaf(z, av[c], p);
            }
            // reduce within the 16-lane head group (xor 8/4/2/1 stays in-group)
            p += __shfl_xor(p, 8, 64);
            p += __shfl_xor(p, 4, 64);
            p += __shfl_xor(p, 2, 64);
            p += __shfl_xor(p, 1, 64);
            if (!pv) p = -INFINITY;
            float w = __expf(fminf(p, 85.f));   // per-(edge,head) weight
            s += w;
#pragma unroll
            for (int c = 0; c < 8; ++c) acc[c] = fmaf(w, v[c], acc[c]);

            if (have_next) { u = un; pv = nv; }
            i1 = i2;
        }
    }

    // merge the 2 edge slots (lane^32 holds matching (head,channel))
    s += __shfl_xor(s, 32, 64);
#pragma unroll
    for (int c = 0; c < 8; ++c) acc[c] += __shfl_xor(acc[c], 32, 64);

    int deg = end - beg;
    float inv = (deg > 0) ? 1.f / (s * (float)deg) : 0.f;
    float o8[8];
#pragma unroll
    for (int c = 0; c < 8; ++c) o8[c] = acc[c] * inv;
    if (bias != nullptr) {
#pragma unroll
        for (int c = 0; c < 8; ++c) o8[c] += bias[cb + c];
    }
    if (g == 0) {
        union { uint4 u; __hip_bfloat16 hh[8]; } pk;
#pragma unroll
        for (int c = 0; c < 8; ++c) pk.hh[c] = __float2bfloat16(o8[c]);
        *(uint4*)(outb + (size_t)dst * obstride + cb) = pk.u;   // 512B contiguous
    }
}

// C=2, H=1 final layer: one thread per dst (fp32 xl/xr).
__global__ void gat_c2(const float* __restrict__ xl, const float* __restrict__ xr,
                       const int* __restrict__ row_off, const int* __restrict__ col,
                       const float* __restrict__ att, const float* __restrict__ bias,
                       float* __restrict__ out, int n_dst) {
    int dst = blockIdx.x * blockDim.x + threadIdx.x;
    if (dst >= n_dst) return;
    float x0 = xr[(size_t)dst * 2], x1 = xr[(size_t)dst * 2 + 1];
    float a0 = att[0], a1 = att[1];
    int beg = row_off[dst], end = row_off[dst + 1];
    float s = 0.f, acc0 = 0.f, acc1 = 0.f;
    for (int e = beg; e < end; ++e) {
        int src = col[e];
        float v0 = xl[(size_t)src * 2], v1 = xl[(size_t)src * 2 + 1];
        float z0 = v0 + x0; z0 = fmaxf(z0, NEG_SLOPE * z0);
        float z1 = v1 + x1; z1 = fmaxf(z1, NEG_SLOPE * z1);
        float p = fmaf(z0, a0, z1 * a1);
        float w = __expf(fminf(p, 85.f));
        s += w;
        acc0 = fmaf(w, v0, acc0);
        acc1 = fmaf(w, v1, acc1);
    }
    int deg = end - beg;
    float o0 = 0.f, o1 = 0.f;
    if (deg > 0) {
        float inv = 1.f / (s * (float)deg);
        o0 = acc0 * inv;
        o1 = acc1 * inv;
    }
    out[(size_t)dst * 2 + 0] = o0 + bias[0];
    out[(size_t)dst * 2 + 1] = o1 + bias[1];
}

// ---------------------------------------------------------------- BatchNorm stats (deterministic)
// PBN=2048 partial blocks (8/CU; 256 blocks was 9.7% occ, latency-bound).
__global__ void bn_partial_d(const __hip_bfloat16* __restrict__ x, float* __restrict__ part,
                             int Nr, int rpb) {
    int C = blockDim.x;
    int c = threadIdx.x;
    int b = blockIdx.x;
    int r0 = b * rpb;
    int r1 = r0 + rpb; if (r1 > Nr) r1 = Nr;
    float s = 0.f, q = 0.f;
    for (int r = r0; r < r1; ++r) {
        float v = __bfloat162float(x[(size_t)r * C + c]);
        s += v;
        q = fmaf(v, v, q);
    }
    part[(size_t)b * C + c] = s;
    part[(size_t)PBN * 256 + (size_t)b * C + c] = q;
}

// one wave per channel; lanes sum PBN/64=32 partials each, fixed-order tree.
__global__ void bn_finalize_w(const float* __restrict__ part,
                              const float* __restrict__ g, const float* __restrict__ b,
                              float* __restrict__ scale, float* __restrict__ shift,
                              int Nr, int C) {
    int c = (blockIdx.x * blockDim.x + threadIdx.x) >> 6;
    int lane = threadIdx.x & 63;
    if (c >= C) return;
    float s = 0.f, q = 0.f;
    for (int blk = lane; blk < PBN; blk += 64) {
        s += part[(size_t)blk * C + c];
        q += part[(size_t)PBN * 256 + (size_t)blk * C + c];
    }
#pragma unroll
    for (int o = 32; o; o >>= 1) {
        s += __shfl_xor(s, o, 64);
        q += __shfl_xor(q, o, 64);
    }
    if (lane == 0) {
        float mu = s / (float)Nr;
        float var = q / (float)Nr - mu * mu;
        float inv = rsqrtf(var + 1e-5f);
        float a = g[c] * inv;
        scale[c] = a;
        shift[c] = b[c] - mu * a;
    }
}

// ---------------------------------------------------------------- driver
extern "C" void kernel_launch(void* const* d_in, const int* in_sizes, int n_in,
                              void* d_out, int out_size, void* d_ws, size_t ws_size,
                              hipStream_t stream) {
    const float* x_low  = (const float*)d_in[0];
    const float* x_high = (const float*)d_in[1];
    const float* z_std  = (const float*)d_in[2];
    const int* e_low  = (const int*)d_in[3];
    const int* e_l2h  = (const int*)d_in[4];
    const int* e_high = (const int*)d_in[5];
    const float* l1_Wl = (const float*)d_in[6];
    const float* l1_Wr = (const float*)d_in[7];
    const float* l1_att = (const float*)d_in[8];
    const float* l1_b  = (const float*)d_in[9];
    const float* bn1_g = (const float*)d_in[10];
    const float* bn1_b = (const float*)d_in[11];
    const float* l2_Wl = (const float*)d_in[12];
    const float* l2_Wr = (const float*)d_in[13];
    const float* l2_att = (const float*)d_in[14];
    const float* l2_b  = (const float*)d_in[15];
    const float* bn2_g = (const float*)d_in[16];
    const float* bn2_b = (const float*)d_in[17];
    const float* l3_Wl = (const float*)d_in[18];
    const float* l3_Wr = (const float*)d_in[19];
    const float* l3_att = (const float*)d_in[20];
    const float* l3_b  = (const float*)d_in[21];
    const float* lh_Wl = (const float*)d_in[22];
    const float* lh_Wr = (const float*)d_in[23];
    const float* lh_att = (const float*)d_in[24];
    const float* h1_Wl = (const float*)d_in[25];
    const float* h1_Wr = (const float*)d_in[26];
    const float* h1_att = (const float*)d_in[27];
    const float* h1_b  = (const float*)d_in[28];
    const float* bn3_g = (const float*)d_in[29];
    const float* bn3_b = (const float*)d_in[30];
    const float* h2_Wl = (const float*)d_in[31];
    const float* h2_Wr = (const float*)d_in[32];
    const float* h2_att = (const float*)d_in[33];
    const float* h2_b  = (const float*)d_in[34];
    const float* bn4_g = (const float*)d_in[35];
    const float* bn4_b = (const float*)d_in[36];
    const float* h3_Wl = (const float*)d_in[37];
    const float* h3_Wr = (const float*)d_in[38];
    const float* h3_att = (const float*)d_in[39];
    const float* h3_b  = (const float*)d_in[40];

    const int N_low = in_sizes[0] / 125;
    const int N_high = in_sizes[1];
    const int E_low = in_sizes[3] / 2;
    const int E_l2h = in_sizes[4] / 2;
    const int E_high = in_sizes[5] / 2;

    char* ws = (char*)d_ws;
    size_t woff = 0;
    auto walloc = [&](size_t bytes) -> void* {
        void* p = (void*)(ws + woff);
        woff += (bytes + 255) & ~(size_t)255;
        return p;
    };
    __hip_bfloat16* XLR = (__hip_bfloat16*)walloc((size_t)N_high * 512 * 2);
    __hip_bfloat16* A1  = (__hip_bfloat16*)walloc((size_t)N_high * 256 * 2);
    __hip_bfloat16* A2  = (__hip_bfloat16*)walloc((size_t)N_high * 128 * 2);
    __hip_bfloat16* XRo = (__hip_bfloat16*)walloc((size_t)N_high * 128 * 2); // lh outer xr
    __hip_bfloat16* XLOWB = (__hip_bfloat16*)walloc((size_t)N_low * 128 * 2);
    __hip_bfloat16* EHB = (__hip_bfloat16*)walloc((size_t)N_high * 160 * 2);
    float* YL = (float*)walloc((size_t)N_high * 2 * 4);
    float* YR = (float*)walloc((size_t)N_high * 2 * 4);
    int* off_low  = (int*)walloc((size_t)(N_low + 1) * 4);
    int* col_low  = (int*)walloc((size_t)E_low * 4);
    int* off_l2h  = (int*)walloc((size_t)(N_high + 1) * 4);
    int* col_l2h  = (int*)walloc((size_t)E_l2h * 4);
    int* off_high = (int*)walloc((size_t)(N_high + 1) * 4);
    int* col_high = (int*)walloc((size_t)E_high * 4);
    // multisplit CSR state
    const int nc0 = (N_low + CBS - 1) >> CSH;
    const int nc1 = (N_high + CBS - 1) >> CSH;
    const int nc2 = (N_high + CBS - 1) >> CSH;
    const int NBC = nc0 + nc1 + nc2;
    const long Etot = (long)E_low + E_l2h + E_high;
    const long chunk = (Etot + PB - 1) / PB;
    auto capf = [&](int ng) {
        double m = (double)chunk * CBS / ng;
        int c = (int)(m + 8.0 * sqrt(m) + 16.0);
        return (c + 15) & ~15;
    };
    const int cap0 = capf(N_low);
    const int cap1 = capf(N_high);
    const int cap2 = capf(N_high);
    int* cnt2   = (int*)walloc((size_t)PB * NBC * 4);
    int* cstart = (int*)walloc((size_t)(NBC + 1) * 4);
    int* ctot   = (int*)walloc((size_t)(NBC + 1) * 4);
    float* bnpart = (float*)walloc((size_t)2 * PBN * 256 * 4);   // deterministic BN partials
    float* bnsc   = (float*)walloc(512 * 4);             // scale | shift
    float* bb     = (float*)walloc(512 * 4);             // folded gemm bias
    __hip_bfloat16* w_l1 = (__hip_bfloat16*)walloc(512 * 128 * 2);
    __hip_bfloat16* w_l2 = (__hip_bfloat16*)walloc(256 * 256 * 2);
    __hip_bfloat16* w_l3 = (__hip_bfloat16*)walloc(256 * 128 * 2);
    __hip_bfloat16* w_lh = (__hip_bfloat16*)walloc(128 * 128 * 2);
    __hip_bfloat16* w_h1 = (__hip_bfloat16*)walloc(512 * 160 * 2);
    __hip_bfloat16* w_h2 = (__hip_bfloat16*)walloc(256 * 256 * 2);

    int* stage = (int*)XLR;   // PB=1024: ~52 MB needed, 61 MB available; dead until first gemm

    // ---- batched prep
    {
        int o1 = N_low * 128;              // xconv
        int o2 = o1 + N_high * 128;        // outer_xr
        int o3 = o2 + N_high * 32;         // EHB cols 128..159
        int o4 = o3 + 256 * 128;           // w_l1 Wl
        int o5 = o4 + 256 * 128;           // w_l1 Wr
        int o6 = o5 + 128 * 128;           // w_lh
        int o7 = o6 + 256 * 160;           // w_h1 Wl
        int o8 = o7 + 256 * 160;           // w_h1 Wr
        prep_all<<<(o8 + 255) / 256, 256, 0, stream>>>(
            l1_Wl, l1_Wr, lh_Wl, h1_Wl, h1_Wr, x_low, x_high, lh_Wr, z_std,
            w_l1, w_lh, w_h1, XLOWB, XRo, EHB,
            o1, o2, o3, o4, o5, o6, o7, o8);
    }

    // ---- multisplit CSR build for all 3 graphs (4 launches, no global atomics)
    msplitA<<<PB, 256, 0, stream>>>(
        e_low, e_low + E_low, E_low,
        e_l2h, e_l2h + E_l2h, E_l2h,
        e_high, e_high + E_high, E_high,
        nc0, nc1, nc2, cap0, cap1, cap2, stage, cnt2);
    scanC1<<<NBC, 256, 0, stream>>>(cnt2, ctot, NBC);
    scanC2<<<1, 64, 0, stream>>>(ctot, cstart, NBC, nc0, nc1);
    fineB<<<NBC, 1024, 0, stream>>>(cnt2, cstart, stage,
                                    nc0, nc1, nc2, cap0, cap1, cap2,
                                    off_low, col_low, N_low,
                                    off_l2h, col_l2h, N_high,
                                    off_high, col_high, N_high);

    auto gemm = [&](const __hip_bfloat16* A, const __hip_bfloat16* Bt, __hip_bfloat16* C,
                    int M, int N, int Kp, const float* bias) {
        dim3 g(N / 128, (M + 127) / 128);
        if (Kp == 128)      gemm_t<128, 128><<<g, 256, 0, stream>>>(A, Bt, C, bias, M, N);
        else if (Kp == 160) gemm_t<160, 160><<<g, 256, 0, stream>>>(A, Bt, C, bias, M, N);
        else                gemm_t<256, 128><<<g, 256, 0, stream>>>(A, Bt, C, bias, M, N);
    };
    auto gat1 = [&](const __hip_bfloat16* xl, int xls, const __hip_bfloat16* xr, int xrs,
                    const int* roff, const int* colv,
                    const float* att, const float* bias,
                    __hip_bfloat16* outb, int obs, int n_dst) {
        long waves = (n_dst + 1) / 2;
        long thr = waves * 64;
        gat_c128_p2<<<(unsigned)((thr + 255) / 256), 256, 0, stream>>>(
            xl, xls, xr, xrs, roff, colv, att, bias, outb, obs, n_dst);
    };
    auto gat2 = [&](const __hip_bfloat16* xl, int xls, const __hip_bfloat16* xr, int xrs,
                    const int* roff, const int* colv,
                    const float* att, const float* bias,
                    __hip_bfloat16* outb, int obs, int n_dst) {
        long thr = (long)n_dst * 64;
        gat_c256h2<<<(unsigned)((thr + 255) / 256), 256, 0, stream>>>(
            xl, xls, xr, xrs, roff, colv, att, bias, outb, obs, n_dst);
    };
    // deterministic BN stats (PBN-parallel partials + wave-per-channel finalize)
    auto bn_stats = [&](__hip_bfloat16* x, const float* g, const float* b, int Nr, int C) {
        int rpb = (Nr + PBN - 1) / PBN;
        bn_partial_d<<<PBN, C, 0, stream>>>(x, bnpart, Nr, rpb);
        bn_finalize_w<<<(C * 64 + 255) / 256, 256, 0, stream>>>(bnpart, g, b, bnsc, bnsc + 256, Nr, C);
    };
    // fold bn (bnsc) into a merged [Wl|Wr] weight + bias pair (one launch)
    auto fold2 = [&](const float* Wl, const float* Wr, __hip_bfloat16* Wt,
                     int K, int Nn, int Kp) {
        dim3 g(Nn, 2);
        wconv_bnfold2<<<g, 256, 0, stream>>>(Wl, Wr, bnsc, bnsc + 256, Wt, bb, K, Nn, Kp);
    };

    // ---- low_net layer 1: 125 -> (H=2) 256   (merged [XL|XR], stride 512)
    gemm(XLOWB, w_l1, XLR, N_low, 512, 128, nullptr);
    gat2(XLR, 512, XLR + 256, 512, off_low, col_low, l1_att, l1_b, A1, 256, N_low);
    bn_stats(A1, bn1_g, bn1_b, N_low, 256);

    // ---- low_net layer 2: 256 -> 128 (BN1 folded into w_l2 + bias)
    fold2(l2_Wl, l2_Wr, w_l2, 256, 128, 256);
    gemm(A1, w_l2, XLR, N_low, 256, 256, bb);
    gat1(XLR, 256, XLR + 128, 256, off_low, col_low, l2_att, l2_b, A2, 128, N_low);
    bn_stats(A2, bn2_g, bn2_b, N_low, 128);

    // ---- low_net layer 3: 128 -> 128 (BN2 folded into w_l3 + bias)
    fold2(l3_Wl, l3_Wr, w_l3, 128, 128, 128);
    gemm(A2, w_l3, XLR, N_low, 256, 128, bb);
    gat1(XLR, 256, XLR + 128, 256, off_low, col_low, l3_att, l3_b, A1, 128, N_low);

    // ---- bipartite low2high -> EHB[N_high][160] = [gat 0..127 | z | pad] (pad/z pre-inited)
    gemm(A1, w_lh, XLR, N_low, 128, 128, nullptr);   // xl only, stride 128
    gat1(XLR, 128, XRo, 128, off_l2h, col_l2h, lh_att, nullptr, EHB, 160, N_high);

    // ---- high_net layer 1: 129(perm,pad160) -> (H=2) 256   (merged, stride 512)
    gemm(EHB, w_h1, XLR, N_high, 512, 160, nullptr);
    gat2(XLR, 512, XLR + 256, 512, off_high, col_high, h1_att, h1_b, A1, 256, N_high);
    bn_stats(A1, bn3_g, bn3_b, N_high, 256);

    // ---- high_net layer 2: 256 -> 128 (BN3 folded into w_h2 + bias)
    fold2(h2_Wl, h2_Wr, w_h2, 256, 128, 256);
    gemm(A1, w_h2, XLR, N_high, 256, 256, bb);
    gat1(XLR, 256, XLR + 128, 256, off_high, col_high, h2_att, h2_b, A2, 128, N_high);
    bn_stats(A2, bn4_g, bn4_b, N_high, 128);

    // ---- high_net layer 3: 128 -> 2 (BN4 applied inline in f32; one pass over A2)
    gemm_n22_bn<<<(N_high + 255) / 256, 256, 0, stream>>>(A2, h3_Wl, h3_Wr,
                                                          bnsc, bnsc + 256, YL, YR, N_high, 128);
    gat_c2<<<(N_high + 255) / 256, 256, 0, stream>>>(YL, YR, off_high, col_high,
                                                     h3_att, h3_b, (float*)d_out, N_high);
}